// Round 1
// baseline (96.308 us; speedup 1.0000x reference)
//
#include <hip/hip_runtime.h>

#define NB 256       // batch
#define NQ 900       // queries / K
#define NC 91        // classes
#define QC (NQ * NC) // 81900
#define NF4 (QC / 4) // 20475 (QC % 4 == 0)
#define NT 512
#define NBIN 16384
#define CHUNK (NBIN / NT) // 32
#define CAP 2048

__device__ __forceinline__ unsigned int mono_key(float x) {
    unsigned int u = __float_as_uint(x);
    return (u & 0x80000000u) ? ~u : (u | 0x80000000u);
}

__global__ __launch_bounds__(NT, 1) void postprocess_topk(
    const float* __restrict__ logits, const float* __restrict__ boxes,
    const float* __restrict__ tsz, float* __restrict__ out) {
    __shared__ unsigned int hist[NBIN];
    __shared__ unsigned long long cand[CAP];
    __shared__ unsigned int csum[NT];
    __shared__ unsigned int s_b1;
    __shared__ unsigned int s_cnt;

    const unsigned int tid = threadIdx.x;
    const unsigned int b = blockIdx.x;
    const float4* row = (const float4*)(logits + (size_t)b * QC);

    for (unsigned int i = tid; i < NBIN; i += NT) hist[i] = 0;
    if (tid == 0) s_cnt = 0;
    __syncthreads();

    // ---- pass 1: histogram of top-14 bits of monotonic key ----
    for (unsigned int i = tid; i < NF4; i += NT) {
        float4 v = row[i];
        #pragma unroll
        for (int j = 0; j < 4; ++j) {
            float x = (&v.x)[j];
            atomicAdd(&hist[mono_key(x) >> 18], 1u);
        }
    }
    __syncthreads();

    // ---- chunk sums + suffix scan to locate threshold bin ----
    {
        unsigned int s = 0;
        const unsigned int base = tid * CHUNK;
        #pragma unroll
        for (unsigned int j = 0; j < CHUNK; ++j) s += hist[base + j];
        csum[tid] = s;
    }
    __syncthreads();
    for (unsigned int off = 1; off < NT; off <<= 1) {
        unsigned int v = csum[tid];
        unsigned int a = (tid + off < NT) ? csum[tid + off] : 0;
        __syncthreads();
        csum[tid] = v + a;
        __syncthreads();
    }
    // unique crossing chunk: csum non-increasing, csum[0] = 81900 >= 900
    if (csum[tid] >= NQ && (tid == NT - 1 || csum[tid + 1] < NQ)) {
        unsigned int running = (tid == NT - 1) ? 0u : csum[tid + 1];
        const unsigned int base = tid * CHUNK;
        unsigned int bin = base + CHUNK;
        unsigned int b1 = base;
        for (unsigned int j = 0; j < CHUNK; ++j) {
            --bin;
            running += hist[bin];
            if (running >= NQ) { b1 = bin; break; }
        }
        s_b1 = b1;
    }
    __syncthreads();
    const unsigned int b1 = s_b1;

    // ---- pass 2: gather all candidates with key-bin >= b1 ----
    for (unsigned int i = tid; i < NF4; i += NT) {
        float4 v = row[i];
        #pragma unroll
        for (int j = 0; j < 4; ++j) {
            float x = (&v.x)[j];
            unsigned int key = mono_key(x);
            if ((key >> 18) >= b1) {
                unsigned int pos = atomicAdd(&s_cnt, 1u);
                if (pos < CAP)
                    cand[pos] = ((unsigned long long)key << 32) |
                                (unsigned int)(i * 4 + j);
            }
        }
    }
    __syncthreads();
    const unsigned int n = min(s_cnt, (unsigned int)CAP);

    // ---- convert to sort items: (asuint(p32) << 32) | ~idx ----
    for (unsigned int i = tid; i < CAP; i += NT) {
        unsigned long long item = 0ull;
        if (i < n) {
            unsigned long long kc = cand[i];
            unsigned int key = (unsigned int)(kc >> 32);
            unsigned int idx = (unsigned int)kc;
            unsigned int u = (key & 0x80000000u) ? (key & 0x7fffffffu) : ~key;
            float x = __uint_as_float(u);
            float p = (float)(1.0 / (1.0 + exp(-(double)x)));
            item = ((unsigned long long)__float_as_uint(p) << 32) |
                   (unsigned int)(~idx);
        }
        cand[i] = item; // own slot: no race
    }

    // ---- bitonic sort, descending (=> p desc, idx asc on ties) ----
    for (unsigned int k = 2; k <= CAP; k <<= 1) {
        for (unsigned int j = k >> 1; j > 0; j >>= 1) {
            __syncthreads();
            for (unsigned int i = tid; i < CAP; i += NT) {
                unsigned int l = i ^ j;
                if (l > i) {
                    unsigned long long a = cand[i], c = cand[l];
                    bool up = ((i & k) == 0);
                    if (up ? (a < c) : (a > c)) { cand[i] = c; cand[l] = a; }
                }
            }
        }
    }
    __syncthreads();

    // ---- emit top-900: scores, labels, scaled boxes ----
    const float img_h = tsz[2 * b];
    const float img_w = tsz[2 * b + 1];
    float* out_scores = out;
    float* out_labels = out + (size_t)NB * NQ;
    float4* out_boxes = (float4*)(out + (size_t)2 * NB * NQ);
    const float4* boxes4 = (const float4*)boxes;

    for (unsigned int r = tid; r < NQ; r += NT) {
        unsigned long long item = cand[r];
        float p = __uint_as_float((unsigned int)(item >> 32));
        unsigned int idx = ~((unsigned int)item);
        unsigned int q = idx / NC;
        unsigned int lab = idx - q * NC;
        float4 bx = boxes4[b * NQ + q];
        float x0 = (bx.x - 0.5f * bx.z) * img_w;
        float y0 = (bx.y - 0.5f * bx.w) * img_h;
        float x1 = (bx.x + 0.5f * bx.z) * img_w;
        float y1 = (bx.y + 0.5f * bx.w) * img_h;
        out_scores[(size_t)b * NQ + r] = p;
        out_labels[(size_t)b * NQ + r] = (float)lab;
        out_boxes[(size_t)b * NQ + r] = make_float4(x0, y0, x1, y1);
    }
}

extern "C" void kernel_launch(void* const* d_in, const int* in_sizes, int n_in,
                              void* d_out, int out_size, void* d_ws, size_t ws_size,
                              hipStream_t stream) {
    const float* logits = (const float*)d_in[0];
    const float* boxes = (const float*)d_in[1];
    const float* tsz = (const float*)d_in[2];
    float* out = (float*)d_out;
    postprocess_topk<<<NB, NT, 0, stream>>>(logits, boxes, tsz, out);
}

// Round 2
// 55.188 us; speedup vs baseline: 1.7451x; 1.7451x over previous
//
#include <hip/hip_runtime.h>

#define NB 256
#define NQ 900
#define NC 91
#define QC (NQ * NC)   // 81900
#define NF4 (QC / 4)   // 20475

#define HBINS 1024
#define PREBIN 320     // bin of x = 2.0  (bin = floor((x+8)*32))
#define CAP 4096       // global candidate cap per row
#define LCAP 1024      // per-slice LDS candidate cap

#define SLICES 8
#define F4S 2560       // ceil(20475/8)
#define NTA 256
#define NTC 512

// ws layout (bytes)
#define CNT_OFF   0
#define HIST_OFF  1024
#define CAND_OFF  (1024 + NB * HBINS * 4)     // 1,049,600
#define ZERO_BYTES CAND_OFF

__device__ __forceinline__ int bin_of(float x) {
    int b = (int)floorf((x + 8.0f) * 32.0f);
    return max(0, min(HBINS - 1, b));
}

// ---------------- Kernel A: stream + histogram + pre-gather ----------------
__global__ __launch_bounds__(NTA, 4) void hist_gather(
    const float* __restrict__ logits, unsigned int* __restrict__ g_cnt,
    unsigned int* __restrict__ g_hist, unsigned long long* __restrict__ g_cand) {
    __shared__ unsigned int hist[HBINS];
    __shared__ unsigned long long lc[LCAP];
    __shared__ unsigned int l_cnt;
    __shared__ unsigned int l_base;

    const unsigned int tid = threadIdx.x;
    const unsigned int b = blockIdx.x >> 3;
    const unsigned int s = blockIdx.x & 7;

    for (unsigned int i = tid; i < HBINS; i += NTA) hist[i] = 0;
    if (tid == 0) l_cnt = 0;
    __syncthreads();

    const float4* row = (const float4*)(logits + (size_t)b * QC);
    const unsigned int beg = s * F4S;
    const unsigned int end = min(beg + F4S, (unsigned int)NF4);
    for (unsigned int i = beg + tid; i < end; i += NTA) {
        float4 v = row[i];
        #pragma unroll
        for (int j = 0; j < 4; ++j) {
            float x = (&v.x)[j];
            int bn = bin_of(x);
            atomicAdd(&hist[bn], 1u);
            if (bn >= PREBIN) {
                unsigned int p = atomicAdd(&l_cnt, 1u);
                if (p < LCAP)
                    lc[p] = ((unsigned long long)__float_as_uint(x) << 32) |
                            (unsigned int)(i * 4u + j);
            }
        }
    }
    __syncthreads();

    unsigned int* gh = g_hist + (size_t)b * HBINS;
    for (unsigned int i = tid; i < HBINS; i += NTA) {
        unsigned int h = hist[i];
        if (h) atomicAdd(&gh[i], h);
    }

    unsigned int raw = l_cnt;
    unsigned int n = min(raw, (unsigned int)LCAP);
    if (tid == 0) {
        // if LDS buffer overflowed, poison the count past CAP -> slow path in C
        unsigned int add = n + ((raw > LCAP) ? (unsigned int)(CAP + 1) : 0u);
        l_base = atomicAdd(&g_cnt[b], add);
    }
    __syncthreads();
    const unsigned int base = l_base;
    unsigned long long* gc = g_cand + (size_t)b * CAP;
    for (unsigned int i = tid; i < n; i += NTA) {
        unsigned int p = base + i;
        if (p < CAP) gc[p] = lc[i];
    }
}

// ---------------- Kernel C: threshold + filter + sort + emit ----------------
__global__ __launch_bounds__(NTC, 1) void select_sort_emit(
    const float* __restrict__ logits, const float* __restrict__ boxes,
    const float* __restrict__ tsz, const unsigned int* __restrict__ g_cnt,
    const unsigned int* __restrict__ g_hist,
    const unsigned long long* __restrict__ g_cand, float* __restrict__ out) {
    __shared__ unsigned int hist[HBINS];
    __shared__ unsigned int csum[NTC];
    __shared__ unsigned long long sbuf[2048];
    __shared__ unsigned int s_cnt;
    __shared__ unsigned int s_b1;

    const unsigned int tid = threadIdx.x;
    const unsigned int b = blockIdx.x;

    const unsigned int* gh = g_hist + (size_t)b * HBINS;
    for (unsigned int i = tid; i < HBINS; i += NTC) hist[i] = gh[i];
    if (tid == 0) s_cnt = 0;
    __syncthreads();

    // suffix scan over 1024 bins (2 bins per thread)
    csum[tid] = hist[2 * tid] + hist[2 * tid + 1];
    __syncthreads();
    for (unsigned int off = 1; off < NTC; off <<= 1) {
        unsigned int v = csum[tid];
        unsigned int a = (tid + off < NTC) ? csum[tid + off] : 0;
        __syncthreads();
        csum[tid] = v + a;
        __syncthreads();
    }
    if (csum[tid] >= NQ && (tid == NTC - 1 || csum[tid + 1] < NQ)) {
        unsigned int running = (tid == NTC - 1) ? 0u : csum[tid + 1];
        unsigned int b1 = 2 * tid;
        for (int bn = 2 * (int)tid + 1; bn >= 2 * (int)tid; --bn) {
            running += hist[bn];
            if (running >= NQ) { b1 = (unsigned int)bn; break; }
        }
        s_b1 = b1;
    }
    __syncthreads();
    const unsigned int b1 = s_b1;
    const unsigned int cnt = g_cnt[b];
    const bool fast = (b1 >= PREBIN) && (cnt <= CAP);

    if (fast) {
        const unsigned long long* gc = g_cand + (size_t)b * CAP;
        for (unsigned int i = tid; i < cnt; i += NTC) {
            unsigned long long kc = gc[i];
            float x = __uint_as_float((unsigned int)(kc >> 32));
            if (bin_of(x) >= (int)b1) {
                unsigned int idx = (unsigned int)kc;
                float p = (float)(1.0 / (1.0 + exp(-(double)x)));
                unsigned int pos = atomicAdd(&s_cnt, 1u);
                if (pos < 2048)
                    sbuf[pos] = ((unsigned long long)__float_as_uint(p) << 32) |
                                (unsigned int)(~idx);
            }
        }
    } else {
        const float4* row = (const float4*)(logits + (size_t)b * QC);
        for (unsigned int i = tid; i < NF4; i += NTC) {
            float4 v = row[i];
            #pragma unroll
            for (int j = 0; j < 4; ++j) {
                float x = (&v.x)[j];
                if (bin_of(x) >= (int)b1) {
                    unsigned int idx = i * 4u + j;
                    float p = (float)(1.0 / (1.0 + exp(-(double)x)));
                    unsigned int pos = atomicAdd(&s_cnt, 1u);
                    if (pos < 2048)
                        sbuf[pos] = ((unsigned long long)__float_as_uint(p) << 32) |
                                    (unsigned int)(~idx);
                }
            }
        }
    }
    __syncthreads();
    const unsigned int n = min(s_cnt, 2048u);
    const unsigned int NS = (n <= 1024u) ? 1024u : 2048u;
    for (unsigned int i = n + tid; i < NS; i += NTC) sbuf[i] = 0ull;

    // bitonic sort, descending => (p desc, idx asc)
    for (unsigned int k = 2; k <= NS; k <<= 1) {
        for (unsigned int j = k >> 1; j > 0; j >>= 1) {
            __syncthreads();
            for (unsigned int i = tid; i < NS; i += NTC) {
                unsigned int l = i ^ j;
                if (l > i) {
                    unsigned long long a = sbuf[i], c = sbuf[l];
                    bool up = ((i & k) == 0);
                    if (up ? (a < c) : (a > c)) { sbuf[i] = c; sbuf[l] = a; }
                }
            }
        }
    }
    __syncthreads();

    const float img_h = tsz[2 * b];
    const float img_w = tsz[2 * b + 1];
    float* out_scores = out;
    float* out_labels = out + (size_t)NB * NQ;
    float4* out_boxes = (float4*)(out + (size_t)2 * NB * NQ);
    const float4* boxes4 = (const float4*)boxes;

    for (unsigned int r = tid; r < NQ; r += NTC) {
        unsigned long long item = sbuf[r];
        float p = __uint_as_float((unsigned int)(item >> 32));
        unsigned int idx = ~((unsigned int)item);
        unsigned int q = idx / NC;
        unsigned int lab = idx - q * NC;
        float4 bx = boxes4[b * NQ + q];
        float x0 = (bx.x - 0.5f * bx.z) * img_w;
        float y0 = (bx.y - 0.5f * bx.w) * img_h;
        float x1 = (bx.x + 0.5f * bx.z) * img_w;
        float y1 = (bx.y + 0.5f * bx.w) * img_h;
        out_scores[(size_t)b * NQ + r] = p;
        out_labels[(size_t)b * NQ + r] = (float)lab;
        out_boxes[(size_t)b * NQ + r] = make_float4(x0, y0, x1, y1);
    }
}

extern "C" void kernel_launch(void* const* d_in, const int* in_sizes, int n_in,
                              void* d_out, int out_size, void* d_ws, size_t ws_size,
                              hipStream_t stream) {
    const float* logits = (const float*)d_in[0];
    const float* boxes = (const float*)d_in[1];
    const float* tsz = (const float*)d_in[2];
    float* out = (float*)d_out;

    unsigned char* ws = (unsigned char*)d_ws;
    unsigned int* g_cnt = (unsigned int*)(ws + CNT_OFF);
    unsigned int* g_hist = (unsigned int*)(ws + HIST_OFF);
    unsigned long long* g_cand = (unsigned long long*)(ws + CAND_OFF);

    hipMemsetAsync(ws, 0, ZERO_BYTES, stream);
    hist_gather<<<NB * SLICES, NTA, 0, stream>>>(logits, g_cnt, g_hist, g_cand);
    select_sort_emit<<<NB, NTC, 0, stream>>>(logits, boxes, tsz, g_cnt, g_hist,
                                             g_cand, out);
}

// Round 3
// 50.652 us; speedup vs baseline: 1.9014x; 1.0896x over previous
//
#include <hip/hip_runtime.h>

#define NB 256
#define NQ 900
#define NC 91
#define QC (NQ * NC)   // 81900
#define NF4 (QC / 4)   // 20475

#define HBINS 1024
#define PREBIN 320     // bin of x = 2.0  (bin = floor((x+8)*32))
#define SLICES 8
#define SCAP 512       // per-slice candidate cap (expect ~233 +/- 15)
#define F4S 2560       // ceil(20475/8)
#define NTA 256
#define NTC 512

// ws layout (bytes); no zero-init required: every byte read is written first
#define CNT_OFF   0                               // 256*8*4   = 8 KB
#define HIST_OFF  (NB * SLICES * 4)               // 8 MB
#define CAND_OFF  (HIST_OFF + NB * SLICES * HBINS * 4)
// total: 8KB + 8MB + 8MB = ~16.8 MB (<< ws_size)

__device__ __forceinline__ int bin_of(float x) {
    int b = (int)floorf((x + 8.0f) * 32.0f);
    return max(0, min(HBINS - 1, b));
}

// ---------- Kernel A: stream + per-slice histogram + pre-gather ----------
__global__ __launch_bounds__(NTA, 4) void hist_gather(
    const float* __restrict__ logits, unsigned int* __restrict__ g_cnt,
    unsigned int* __restrict__ g_hist, unsigned long long* __restrict__ g_cand) {
    __shared__ unsigned int hist[HBINS];
    __shared__ unsigned long long lc[SCAP];
    __shared__ unsigned int l_cnt;

    const unsigned int tid = threadIdx.x;
    const unsigned int b = blockIdx.x >> 3;
    const unsigned int s = blockIdx.x & 7;
    const unsigned int sl = blockIdx.x; // b*8+s

    for (unsigned int i = tid; i < HBINS; i += NTA) hist[i] = 0;
    if (tid == 0) l_cnt = 0;
    __syncthreads();

    const float4* row = (const float4*)(logits + (size_t)b * QC);
    const unsigned int beg = s * F4S;
    const unsigned int end = min(beg + F4S, (unsigned int)NF4);
    for (unsigned int i = beg + tid; i < end; i += NTA) {
        float4 v = row[i];
        #pragma unroll
        for (int j = 0; j < 4; ++j) {
            float x = (&v.x)[j];
            int bn = bin_of(x);
            atomicAdd(&hist[bn], 1u);
            if (bn >= PREBIN) {
                unsigned int p = atomicAdd(&l_cnt, 1u);
                if (p < SCAP)
                    lc[p] = ((unsigned long long)__float_as_uint(x) << 32) |
                            (unsigned int)(i * 4u + j);
            }
        }
    }
    __syncthreads();

    // plain coalesced stores — no zero-init, no global atomics
    unsigned int* gh = g_hist + (size_t)sl * HBINS;
    for (unsigned int i = tid; i < HBINS; i += NTA) gh[i] = hist[i];

    const unsigned int raw = l_cnt;
    const unsigned int n = min(raw, (unsigned int)SCAP);
    unsigned long long* gc = g_cand + (size_t)sl * SCAP;
    for (unsigned int i = tid; i < n; i += NTA) gc[i] = lc[i];
    if (tid == 0) g_cnt[sl] = raw; // raw>SCAP signals slow path
}

// ---------- Kernel C: threshold + filter + sort + emit ----------
__global__ __launch_bounds__(NTC, 1) void select_sort_emit(
    const float* __restrict__ logits, const float* __restrict__ boxes,
    const float* __restrict__ tsz, const unsigned int* __restrict__ g_cnt,
    const unsigned int* __restrict__ g_hist,
    const unsigned long long* __restrict__ g_cand, float* __restrict__ out) {
    __shared__ unsigned int hist[HBINS];
    __shared__ unsigned int csum[NTC];
    __shared__ unsigned long long sbuf[2048];
    __shared__ unsigned int s_cnt;
    __shared__ unsigned int s_b1;
    __shared__ unsigned int scnts[SLICES];

    const unsigned int tid = threadIdx.x;
    const unsigned int b = blockIdx.x;

    // sum the 8 slice histograms
    const unsigned int* gh = g_hist + (size_t)b * SLICES * HBINS;
    for (unsigned int i = tid; i < HBINS; i += NTC) {
        unsigned int h = 0;
        #pragma unroll
        for (int s = 0; s < SLICES; ++s) h += gh[s * HBINS + i];
        hist[i] = h;
    }
    if (tid == 0) s_cnt = 0;
    if (tid < SLICES) scnts[tid] = g_cnt[b * SLICES + tid];
    __syncthreads();

    // suffix scan over 1024 bins (2 bins per thread)
    csum[tid] = hist[2 * tid] + hist[2 * tid + 1];
    __syncthreads();
    for (unsigned int off = 1; off < NTC; off <<= 1) {
        unsigned int v = csum[tid];
        unsigned int a = (tid + off < NTC) ? csum[tid + off] : 0;
        __syncthreads();
        csum[tid] = v + a;
        __syncthreads();
    }
    if (csum[tid] >= NQ && (tid == NTC - 1 || csum[tid + 1] < NQ)) {
        unsigned int running = (tid == NTC - 1) ? 0u : csum[tid + 1];
        unsigned int b1 = 2 * tid;
        for (int bn = 2 * (int)tid + 1; bn >= 2 * (int)tid; --bn) {
            running += hist[bn];
            if (running >= NQ) { b1 = (unsigned int)bn; break; }
        }
        s_b1 = b1;
    }
    __syncthreads();
    const unsigned int b1 = s_b1;

    bool fast = (b1 >= PREBIN);
    for (int s = 0; s < SLICES; ++s) fast = fast && (scnts[s] <= SCAP);

    if (fast) {
        const unsigned long long* gc = g_cand + (size_t)b * SLICES * SCAP;
        for (unsigned int slot = tid; slot < SLICES * SCAP; slot += NTC) {
            unsigned int s = slot >> 9;       // / SCAP
            unsigned int i = slot & (SCAP - 1);
            if (i < scnts[s]) {
                unsigned long long kc = gc[slot];
                float x = __uint_as_float((unsigned int)(kc >> 32));
                if (bin_of(x) >= (int)b1) {
                    unsigned int idx = (unsigned int)kc;
                    float p = (float)(1.0 / (1.0 + exp(-(double)x)));
                    unsigned int pos = atomicAdd(&s_cnt, 1u);
                    if (pos < 2048)
                        sbuf[pos] = ((unsigned long long)__float_as_uint(p) << 32) |
                                    (unsigned int)(~idx);
                }
            }
        }
    } else {
        const float4* row = (const float4*)(logits + (size_t)b * QC);
        for (unsigned int i = tid; i < NF4; i += NTC) {
            float4 v = row[i];
            #pragma unroll
            for (int j = 0; j < 4; ++j) {
                float x = (&v.x)[j];
                if (bin_of(x) >= (int)b1) {
                    unsigned int idx = i * 4u + j;
                    float p = (float)(1.0 / (1.0 + exp(-(double)x)));
                    unsigned int pos = atomicAdd(&s_cnt, 1u);
                    if (pos < 2048)
                        sbuf[pos] = ((unsigned long long)__float_as_uint(p) << 32) |
                                    (unsigned int)(~idx);
                }
            }
        }
    }
    __syncthreads();
    const unsigned int n = min(s_cnt, 2048u);
    const unsigned int NS = (n <= 1024u) ? 1024u : 2048u;
    for (unsigned int i = n + tid; i < NS; i += NTC) sbuf[i] = 0ull;

    // bitonic sort, descending => (p desc, idx asc)
    for (unsigned int k = 2; k <= NS; k <<= 1) {
        for (unsigned int j = k >> 1; j > 0; j >>= 1) {
            __syncthreads();
            for (unsigned int i = tid; i < NS; i += NTC) {
                unsigned int l = i ^ j;
                if (l > i) {
                    unsigned long long a = sbuf[i], c = sbuf[l];
                    bool up = ((i & k) == 0);
                    if (up ? (a < c) : (a > c)) { sbuf[i] = c; sbuf[l] = a; }
                }
            }
        }
    }
    __syncthreads();

    const float img_h = tsz[2 * b];
    const float img_w = tsz[2 * b + 1];
    float* out_scores = out;
    float* out_labels = out + (size_t)NB * NQ;
    float4* out_boxes = (float4*)(out + (size_t)2 * NB * NQ);
    const float4* boxes4 = (const float4*)boxes;

    for (unsigned int r = tid; r < NQ; r += NTC) {
        unsigned long long item = sbuf[r];
        float p = __uint_as_float((unsigned int)(item >> 32));
        unsigned int idx = ~((unsigned int)item);
        unsigned int q = idx / NC;
        unsigned int lab = idx - q * NC;
        float4 bx = boxes4[b * NQ + q];
        float x0 = (bx.x - 0.5f * bx.z) * img_w;
        float y0 = (bx.y - 0.5f * bx.w) * img_h;
        float x1 = (bx.x + 0.5f * bx.z) * img_w;
        float y1 = (bx.y + 0.5f * bx.w) * img_h;
        out_scores[(size_t)b * NQ + r] = p;
        out_labels[(size_t)b * NQ + r] = (float)lab;
        out_boxes[(size_t)b * NQ + r] = make_float4(x0, y0, x1, y1);
    }
}

extern "C" void kernel_launch(void* const* d_in, const int* in_sizes, int n_in,
                              void* d_out, int out_size, void* d_ws, size_t ws_size,
                              hipStream_t stream) {
    const float* logits = (const float*)d_in[0];
    const float* boxes = (const float*)d_in[1];
    const float* tsz = (const float*)d_in[2];
    float* out = (float*)d_out;

    unsigned char* ws = (unsigned char*)d_ws;
    unsigned int* g_cnt = (unsigned int*)(ws + CNT_OFF);
    unsigned int* g_hist = (unsigned int*)(ws + HIST_OFF);
    unsigned long long* g_cand = (unsigned long long*)(ws + CAND_OFF);

    hist_gather<<<NB * SLICES, NTA, 0, stream>>>(logits, g_cnt, g_hist, g_cand);
    select_sort_emit<<<NB, NTC, 0, stream>>>(logits, boxes, tsz, g_cnt, g_hist,
                                             g_cand, out);
}

// Round 4
// 50.568 us; speedup vs baseline: 1.9045x; 1.0017x over previous
//
#include <hip/hip_runtime.h>

#define NB 256
#define NQ 900
#define NC 91
#define QC (NQ * NC)   // 81900
#define NF4 (QC / 4)   // 20475

#define NSL 16         // slices per row
#define F4S 1280       // ceil(NF4/NSL)
#define SCAP 256       // per-slice cap (mean ~116, sigma ~11)
#define NTA 256
#define NTC 512
#define CCAP 2048      // per-row candidate cap in C
#define PBINS 4096
#define XTHR 2.0f      // gather threshold; top-900 boundary is x ~ 2.09

// ws: g_cnt[NB*NSL] then g_cand[NB*NSL*SCAP]; no zero-init needed
#define CNT_BYTES (NB * NSL * 4)

__device__ __forceinline__ unsigned int mono_key(float x) {
    unsigned int u = __float_as_uint(x);
    return (u & 0x80000000u) ? ~u : (u | 0x80000000u);
}

// ---------------- Kernel A: stream + filter + compact ----------------
__global__ __launch_bounds__(NTA, 4) void gather_cand(
    const float* __restrict__ logits, unsigned int* __restrict__ g_cnt,
    unsigned long long* __restrict__ g_cand) {
    __shared__ unsigned int l_cnt;
    const unsigned int tid = threadIdx.x;
    const unsigned int sl = blockIdx.x;
    const unsigned int b = sl >> 4;
    const unsigned int s = sl & 15;

    if (tid == 0) l_cnt = 0;
    __syncthreads();

    const float4* row = (const float4*)(logits + (size_t)b * QC);
    unsigned long long* gc = g_cand + (size_t)sl * SCAP;
    const unsigned int beg = s * F4S;
    const unsigned int end = min(beg + F4S, (unsigned int)NF4);
    for (unsigned int i = beg + tid; i < end; i += NTA) {
        float4 v = row[i];
        #pragma unroll
        for (int j = 0; j < 4; ++j) {
            float x = (&v.x)[j];
            if (x >= XTHR) {
                unsigned int p = atomicAdd(&l_cnt, 1u);
                if (p < SCAP)
                    gc[p] = ((unsigned long long)__float_as_uint(x) << 32) |
                            (unsigned int)(i * 4u + j);
            }
        }
    }
    __syncthreads();
    if (tid == 0) g_cnt[sl] = l_cnt;
}

// -------- Kernel C: p32 keys + counting-rank (no sort) + emit --------
__global__ __launch_bounds__(NTC, 1) void select_rank_emit(
    const float* __restrict__ logits, const float* __restrict__ boxes,
    const float* __restrict__ tsz, const unsigned int* __restrict__ g_cnt,
    const unsigned long long* __restrict__ g_cand, float* __restrict__ out) {
    __shared__ unsigned long long cand[CCAP];    // 16 KB
    __shared__ unsigned long long sorted[CCAP];  // 16 KB
    __shared__ unsigned long long fin[NQ];       // 7.2 KB
    __shared__ unsigned int hist[PBINS];         // 16 KB
    __shared__ unsigned int csum[NTC];           // 2 KB
    __shared__ unsigned int scnt[NSL];
    __shared__ unsigned int s_minu, s_maxu, s_n;

    const unsigned int tid = threadIdx.x;
    const unsigned int b = blockIdx.x;

    if (tid < NSL) scnt[tid] = g_cnt[b * NSL + tid];
    if (tid == 0) { s_minu = 0xFFFFFFFFu; s_maxu = 0u; s_n = 0u; }
    __syncthreads();

    unsigned int pre[NSL];
    unsigned int tot = 0;
    bool ok = true;
    #pragma unroll
    for (int s = 0; s < NSL; ++s) {
        pre[s] = tot;
        unsigned int c = scnt[s];
        ok = ok && (c <= SCAP);
        tot += min(c, (unsigned int)SCAP);
    }
    ok = ok && (tot >= NQ + 50) && (tot <= CCAP);

    unsigned int n;
    if (ok) {
        n = tot;
        for (int s = 0; s < NSL; ++s) {
            const unsigned long long* gc = g_cand + (size_t)(b * NSL + s) * SCAP;
            for (unsigned int i = tid; i < scnt[s]; i += NTC)
                cand[pre[s] + i] = gc[i];
        }
    } else {
        // ---- slow path (never taken on this data): exact threshold search ----
        const float4* row = (const float4*)(logits + (size_t)b * QC);
        unsigned int T = 0;
        for (int bit = 31; bit >= 0; --bit) {
            unsigned int cT = T | (1u << bit);
            unsigned int c = 0;
            for (unsigned int i = tid; i < NF4; i += NTC) {
                float4 v = row[i];
                #pragma unroll
                for (int j = 0; j < 4; ++j)
                    c += (mono_key((&v.x)[j]) >= cT) ? 1u : 0u;
            }
            csum[tid] = c;
            __syncthreads();
            for (unsigned int off = NTC / 2; off; off >>= 1) {
                if (tid < off) csum[tid] += csum[tid + off];
                __syncthreads();
            }
            unsigned int total = csum[0];
            __syncthreads();
            if (total >= NQ + 128) T = cT;
        }
        for (unsigned int i = tid; i < NF4; i += NTC) {
            float4 v = row[i];
            #pragma unroll
            for (int j = 0; j < 4; ++j) {
                float x = (&v.x)[j];
                if (mono_key(x) >= T) {
                    unsigned int p = atomicAdd(&s_n, 1u);
                    if (p < CCAP)
                        cand[p] = ((unsigned long long)__float_as_uint(x) << 32) |
                                  (unsigned int)(i * 4u + j);
                }
            }
        }
        __syncthreads();
        n = min(s_n, (unsigned int)CCAP);
    }
    __syncthreads();

    // ---- compute f64-rounded sigmoid keys, track min/max of asuint(p) ----
    for (unsigned int i = tid; i < n; i += NTC) {
        unsigned long long kc = cand[i];
        float x = __uint_as_float((unsigned int)(kc >> 32));
        unsigned int idx = (unsigned int)kc;
        float p = (float)(1.0 / (1.0 + exp(-(double)x)));
        unsigned int pb = __float_as_uint(p);
        atomicMin(&s_minu, pb);
        atomicMax(&s_maxu, pb);
        cand[i] = ((unsigned long long)pb << 32) | (unsigned int)(~idx);
    }
    __syncthreads();

    const unsigned int base = s_minu;
    const unsigned int d = s_maxu - s_minu;  // span-1
    const int hb = d ? (31 - __builtin_clz(d)) : 0;
    const int shift = (hb > 11) ? (hb - 11) : 0;

    for (unsigned int i = tid; i < PBINS; i += NTC) hist[i] = 0;
    __syncthreads();
    for (unsigned int i = tid; i < n; i += NTC) {
        unsigned int bin = ((unsigned int)(cand[i] >> 32) - base) >> shift;
        atomicAdd(&hist[bin], 1u);
    }
    __syncthreads();

    // suffix scan over 4096 bins (8 per thread)
    {
        unsigned int s8 = 0;
        const unsigned int b8 = tid * 8;
        #pragma unroll
        for (int k = 0; k < 8; ++k) s8 += hist[b8 + k];
        csum[tid] = s8;
    }
    __syncthreads();
    for (unsigned int off = 1; off < NTC; off <<= 1) {
        unsigned int v = csum[tid];
        unsigned int a = (tid + off < NTC) ? csum[tid + off] : 0;
        __syncthreads();
        csum[tid] = v + a;
        __syncthreads();
    }
    {
        unsigned int running = (tid == NTC - 1) ? 0u : csum[tid + 1];
        #pragma unroll
        for (int k = 7; k >= 0; --k) {
            unsigned int bin = tid * 8 + k;
            unsigned int h = hist[bin];
            hist[bin] = running;  // cursor = #elems in strictly higher bins
            running += h;
        }
    }
    __syncthreads();

    // scatter into bin-ordered array
    for (unsigned int i = tid; i < n; i += NTC) {
        unsigned long long key = cand[i];
        unsigned int bin = ((unsigned int)(key >> 32) - base) >> shift;
        unsigned int slot = atomicAdd(&hist[bin], 1u);
        sorted[slot] = key;
    }
    __syncthreads();

    // exact rank = run_start + #{run-mates with greater key}
    for (unsigned int t = tid; t < n; t += NTC) {
        unsigned long long key = sorted[t];
        unsigned int mybin = ((unsigned int)(key >> 32) - base) >> shift;
        int st = (int)t;
        while (st > 0 &&
               (((unsigned int)(sorted[st - 1] >> 32) - base) >> shift) == mybin)
            --st;
        int en = (int)t + 1;
        while (en < (int)n &&
               (((unsigned int)(sorted[en] >> 32) - base) >> shift) == mybin)
            ++en;
        unsigned int pos = (unsigned int)st;
        for (int j = st; j < en; ++j)
            if (sorted[j] > key) ++pos;
        if (pos < NQ) fin[pos] = key;
    }
    __syncthreads();

    // coalesced emit
    const float img_h = tsz[2 * b];
    const float img_w = tsz[2 * b + 1];
    float* out_scores = out;
    float* out_labels = out + (size_t)NB * NQ;
    float4* out_boxes = (float4*)(out + (size_t)2 * NB * NQ);
    const float4* boxes4 = (const float4*)boxes;

    for (unsigned int r = tid; r < NQ; r += NTC) {
        unsigned long long key = fin[r];
        float p = __uint_as_float((unsigned int)(key >> 32));
        unsigned int idx = ~((unsigned int)key);
        unsigned int q = idx / NC;
        unsigned int lab = idx - q * NC;
        float4 bx = boxes4[b * NQ + q];
        float x0 = (bx.x - 0.5f * bx.z) * img_w;
        float y0 = (bx.y - 0.5f * bx.w) * img_h;
        float x1 = (bx.x + 0.5f * bx.z) * img_w;
        float y1 = (bx.y + 0.5f * bx.w) * img_h;
        out_scores[(size_t)b * NQ + r] = p;
        out_labels[(size_t)b * NQ + r] = (float)lab;
        out_boxes[(size_t)b * NQ + r] = make_float4(x0, y0, x1, y1);
    }
}

extern "C" void kernel_launch(void* const* d_in, const int* in_sizes, int n_in,
                              void* d_out, int out_size, void* d_ws, size_t ws_size,
                              hipStream_t stream) {
    const float* logits = (const float*)d_in[0];
    const float* boxes = (const float*)d_in[1];
    const float* tsz = (const float*)d_in[2];
    float* out = (float*)d_out;

    unsigned char* ws = (unsigned char*)d_ws;
    unsigned int* g_cnt = (unsigned int*)ws;
    unsigned long long* g_cand = (unsigned long long*)(ws + CNT_BYTES);

    gather_cand<<<NB * NSL, NTA, 0, stream>>>(logits, g_cnt, g_cand);
    select_rank_emit<<<NB, NTC, 0, stream>>>(logits, boxes, tsz, g_cnt, g_cand,
                                             out);
}